// Round 20
// baseline (243.659 us; speedup 1.0000x reference)
//
#include <hip/hip_runtime.h>
#include <hip/hip_bf16.h>
#include <stdint.h>

#define NB 8192
#define NE 210
#define NS 7
#define NEXP 217
#define NI 8
#define H 128
#define BT 256
#define NTILE (NB / BT)          // 32
// blob per expert: [W1k 4K][bias 2K: bH0k,bH1k,wo,bo][Wh0k 32K][Wh1k 32K]
#define BLOB_STRIDE 71680
#define BIAS_OFF 4096
#define WH0_OFF 6144
#define WH1_OFF 38912
#define SMEM_BYTES 67584         // 2K bias + 64K Wh -> 2 blocks/CU
#define K2 2.8853900817779268f   // 2/ln2 : tanh(x) = 1 - 2/(1+2^(K2 x))
#define TANH_A 4.0
#define IK2 0.34657359027997264f // 1/K2 (poly consumes raw x = a/K2)

// ws layout (bytes); blob ends at 217*71680 = 15,554,560
#define O_COEF 15555584u         // 9 floats poly coeffs
#define O_FT 15560000u           // F_distT bf16 [45][8192]
#define O_CT 16300000u           // F_cosT  bf16 [210][8192]
#define O_ST 19750000u           // F_sinT  bf16 [210][8192]

typedef __attribute__((ext_vector_type(8))) short bf16x8;
typedef __attribute__((ext_vector_type(4))) float f32x4;
typedef __attribute__((ext_vector_type(16))) float f32x16;
typedef __attribute__((ext_vector_type(2))) int i32x2;

union I4V { int4 i; bf16x8 v; unsigned u[4]; };
union C16 { f32x16 v; f32x4 q[4]; };

__device__ __forceinline__ unsigned short f2bf(float f) {
  unsigned u = __float_as_uint(f);
  u += 0x7fffu + ((u >> 16) & 1u);
  return (unsigned short)(u >> 16);
}
// trans-pipe tanh: input pre-scaled by K2 (weights folded)
__device__ __forceinline__ float fast_tanh_s(float xs) {
  float e = __builtin_amdgcn_exp2f(xs);
  return 1.0f - 2.0f * __builtin_amdgcn_rcpf(1.0f + e);
}
// full-rate-pipe tanh: deg-17 odd poly, NAMED SGPR coeffs (no scratch, R13).
// Input is the K2-scaled preact; un-scale with one mul folded into clamp.
__device__ __forceinline__ float poly_tanh(float xs,
    float d0, float d1, float d2, float d3, float d4,
    float d5, float d6, float d7, float d8) {
  float xc = __builtin_amdgcn_fmed3f(xs * IK2, -4.0f, 4.0f);
  float u = xc * xc;
  float q = d8 * u;
  q = q + d7;
  q = __builtin_fmaf(q, u, d6);
  q = __builtin_fmaf(q, u, d5);
  q = __builtin_fmaf(q, u, d4);
  q = __builtin_fmaf(q, u, d3);
  q = __builtin_fmaf(q, u, d2);
  q = __builtin_fmaf(q, u, d1);
  q = __builtin_fmaf(q, u, d0);
  return q * xc;
}
#define PD d0, d1, d2, d3, d4, d5, d6, d7, d8
#define PDECL float d0, float d1, float d2, float d3, float d4, float d5, float d6, float d7, float d8
__device__ __forceinline__ unsigned pk_bf16(float a, float b) {
  unsigned r;
  asm("v_cvt_pk_bf16_f32 %0, %1, %2" : "=v"(r) : "v"(a), "v"(b));
  return r;
}
__device__ __forceinline__ void glds16(const void* g, void* l) {
  __builtin_amdgcn_global_load_lds(
      (const __attribute__((address_space(1))) unsigned int*)g,
      (__attribute__((address_space(3))) unsigned int*)l, 16, 0, 0);
}

// ---- coefficient fit: Chebyshev projection of tanh(A*s), deg 17 odd ------
// (numerically verified by R12/R13 passes, absmax 0.1289)
__global__ void k_fit(float* __restrict__ D) {
  int k = threadIdx.x;   // 64 nodes
  double th = 3.14159265358979323846 * (k + 0.5) / 64.0;
  double s = cos(th);
  double fx = tanh(TANH_A * s);
  double c[9];
  double Tm2 = 1.0, Tm1 = s;
  c[0] = fx * s;
  for (int n = 2; n <= 17; ++n) {
    double T = 2.0 * s * Tm1 - Tm2;
    Tm2 = Tm1; Tm1 = T;
    if (n & 1) c[(n - 1) >> 1] = fx * T;
  }
  for (int m = 0; m < 9; ++m) {
    double v = c[m];
    for (int off = 32; off; off >>= 1) v += __shfl_xor(v, off, 64);
    c[m] = v * (2.0 / 64.0);
  }
  if (k == 0) {
    double prev[18], cur[18], nxt[18], B[18];
    for (int j = 0; j < 18; ++j) { prev[j] = 0; cur[j] = 0; B[j] = 0; }
    prev[0] = 1.0; cur[1] = 1.0;
    B[1] = c[0];
    for (int n = 2; n <= 17; ++n) {
      for (int j = 0; j < 18; ++j) nxt[j] = 2.0 * (j ? cur[j - 1] : 0.0) - prev[j];
      if (n & 1) { int m = (n - 1) >> 1; for (int j = 0; j < 18; ++j) B[j] += c[m] * nxt[j]; }
      for (int j = 0; j < 18; ++j) { prev[j] = cur[j]; cur[j] = nxt[j]; }
    }
    double ap = TANH_A;
    for (int j = 0; j < 9; ++j) {
      D[j] = (float)(B[2 * j + 1] / ap);
      ap *= TANH_A * TANH_A;
    }
  }
}

// ---- transition slice pair (verified R5 permlane map), hybrid acts -------
// Per 4-act subgroup the FIRST act runs on the full-rate pipe (poly), the
// other 3 on the trans pipe (exp/rcp) -> both pipes work concurrently.
__device__ __forceinline__ void trans_pair(const f32x16& a, bf16x8 (&bn)[8], int base,
                                           PDECL) {
#pragma unroll
  for (int half = 0; half < 2; ++half) {
    const int ko = half * 8;
    unsigned P0 = pk_bf16(poly_tanh(a[ko + 0], PD), fast_tanh_s(a[ko + 1]));
    unsigned P1 = pk_bf16(fast_tanh_s(a[ko + 2]), fast_tanh_s(a[ko + 3]));
    unsigned P2 = pk_bf16(poly_tanh(a[ko + 4], PD), fast_tanh_s(a[ko + 5]));
    unsigned P3 = pk_bf16(fast_tanh_s(a[ko + 6]), fast_tanh_s(a[ko + 7]));
    i32x2 s0 = __builtin_amdgcn_permlane32_swap((int)P0, (int)P2, false, false);
    i32x2 s1 = __builtin_amdgcn_permlane32_swap((int)P1, (int)P3, false, false);
    I4V r;
    r.u[0] = (unsigned)s0.x;   // w0
    r.u[1] = (unsigned)s1.x;   // w1
    r.u[2] = (unsigned)s0.y;   // w2
    r.u[3] = (unsigned)s1.y;   // w3
    bn[base + half] = r.v;
  }
}

// ---- hidden layer fused with next transition (mt-outer, R19) -------------
__device__ __forceinline__ void hidden_fused(f32x16 (&acc)[4], const bf16x8 (&bnIn)[8],
                                             bf16x8 (&bnOut)[8],
                                             const uint8_t* wb, const float* biaL,
                                             int row, int hi, int hi4, PDECL) {
  __builtin_amdgcn_s_setprio(1);
#pragma unroll
  for (int mt = 0; mt < 4; ++mt) {
    int soff0 = (hi ^ (row & 15)) << 4;
    bf16x8 aF = *(const bf16x8*)(wb + (mt * 32 + row) * 256 + soff0);
    C16 c0;
#pragma unroll
    for (int i = 0; i < 4; ++i)
      c0.q[i] = *(const f32x4*)(biaL + mt * 32 + i * 8 + hi4);
    acc[mt] = __builtin_amdgcn_mfma_f32_32x32x16_bf16(aF, bnIn[0], c0.v, 0, 0, 0);
#pragma unroll
    for (int kk = 1; kk < 8; ++kk) {
      int soff = ((2 * kk + hi) ^ (row & 15)) << 4;
      bf16x8 aF2 = *(const bf16x8*)(wb + (mt * 32 + row) * 256 + soff);
      acc[mt] = __builtin_amdgcn_mfma_f32_32x32x16_bf16(aF2, bnIn[kk], acc[mt], 0, 0, 0);
    }
    trans_pair(acc[mt], bnOut, 2 * mt, PD);
  }
  __builtin_amdgcn_s_setprio(0);
}

// ---- last hidden layer fused with output tanh-dot (hybrid acts) ----------
__device__ __forceinline__ float hidden_out(f32x16 (&acc)[4], const bf16x8 (&bnIn)[8],
                                            const uint8_t* wb, const float* biaL,
                                            const float* woL,
                                            int row, int hi, int hi4, PDECL) {
  float sum = 0.f;
  __builtin_amdgcn_s_setprio(1);
#pragma unroll
  for (int mt = 0; mt < 4; ++mt) {
    int soff0 = (hi ^ (row & 15)) << 4;
    bf16x8 aF = *(const bf16x8*)(wb + (mt * 32 + row) * 256 + soff0);
    C16 c0;
#pragma unroll
    for (int i = 0; i < 4; ++i)
      c0.q[i] = *(const f32x4*)(biaL + mt * 32 + i * 8 + hi4);
    acc[mt] = __builtin_amdgcn_mfma_f32_32x32x16_bf16(aF, bnIn[0], c0.v, 0, 0, 0);
#pragma unroll
    for (int kk = 1; kk < 8; ++kk) {
      int soff = ((2 * kk + hi) ^ (row & 15)) << 4;
      bf16x8 aF2 = *(const bf16x8*)(wb + (mt * 32 + row) * 256 + soff);
      acc[mt] = __builtin_amdgcn_mfma_f32_32x32x16_bf16(aF2, bnIn[kk], acc[mt], 0, 0, 0);
    }
#pragma unroll
    for (int i = 0; i < 4; ++i) {
      f32x4 wq = *(const f32x4*)(woL + mt * 32 + i * 8 + hi4);
      sum += poly_tanh(acc[mt][4 * i + 0], PD) * wq[0];
      sum += fast_tanh_s(acc[mt][4 * i + 1]) * wq[1];
      sum += fast_tanh_s(acc[mt][4 * i + 2]) * wq[2];
      sum += fast_tanh_s(acc[mt][4 * i + 3]) * wq[3];
    }
  }
  __builtin_amdgcn_s_setprio(0);
  return sum;
}

// ---------------- prep: pack (K2-prescale) + transpose + out-zero ---------
__global__ __launch_bounds__(256) void k_prep(
    const float* __restrict__ W1, const float* __restrict__ Wh,
    const float* __restrict__ W1s, const float* __restrict__ Whs,
    const float* __restrict__ bh, const float* __restrict__ bhs,
    const float* __restrict__ Wo, const float* __restrict__ Wos,
    const float* __restrict__ bo, const float* __restrict__ bos,
    const float* __restrict__ F_dist, const float* __restrict__ F_cos,
    const float* __restrict__ F_sin,
    const float* __restrict__ Zd, const float* __restrict__ Zc,
    const float* __restrict__ Zs,
    uint8_t* __restrict__ blob, uint16_t* __restrict__ FT,
    uint16_t* __restrict__ CT, uint16_t* __restrict__ ST,
    float* __restrict__ outZ) {
  int bid = blockIdx.x;
  if (bid < NEXP * 3) {
    int n = threadIdx.x;
    if (n >= 128) return;
    int e = bid / 3, sec = bid % 3;
    uint8_t* be = blob + (size_t)e * BLOB_STRIDE;
    bool big = e < NE;
    int s = e - NE;
    if (sec == 0) {
      union { int4 v[2]; unsigned short u[16]; } row;
      row.v[0] = make_int4(0, 0, 0, 0);
      row.v[1] = make_int4(0, 0, 0, 0);
      if (big) {
        for (int k = 0; k < NI; ++k) row.u[k] = f2bf(K2 * W1[((size_t)e * NI + k) * H + n]);
      } else {
        for (int k = 0; k < 2; ++k) row.u[k] = f2bf(K2 * W1s[((size_t)s * 2 + k) * H + n]);
      }
      *(int4*)(be + n * 32) = row.v[0];
      *(int4*)(be + n * 32 + 16) = row.v[1];
      float* bsec = (float*)(be + BIAS_OFF);
      bsec[n]       = K2 * (big ? bh[(size_t)e * H + n]        : bhs[(size_t)s * H + n]);
      bsec[128 + n] = K2 * (big ? bh[((size_t)NE + e) * H + n] : bhs[((size_t)NS + s) * H + n]);
      bsec[256 + n] = big ? Wo[(size_t)e * H + n] : Wos[(size_t)s * H + n];
      if (n == 0) bsec[384] = big ? bo[e] : bos[s];
    } else {
      int l = sec - 1;
      union { int4 v[16]; unsigned short u[128]; } row;
      if (big) {
        for (int k = 0; k < H; ++k)
          row.u[k] = f2bf(K2 * Wh[(((size_t)l * NE + e) * H + k) * H + n]);
      } else {
        for (int k = 0; k < H; ++k)
          row.u[k] = f2bf(K2 * Whs[(((size_t)l * NS + s) * H + k) * H + n]);
      }
      int4* dst = (int4*)(be + (l ? WH1_OFF : WH0_OFF) + n * 256);
      for (int c = 0; c < 16; ++c) dst[c] = row.v[c ^ (n & 15)];
    }
  } else if (bid < NEXP * 3 + 32) {
    int tile = bid - NEXP * 3;
    int bb = tile * 256 + threadIdx.x;
    outZ[bb] = 0.f;                     // folded d_out zeroing (32x256 = 8192)
    for (int c = 0; c < 45; ++c) {
      float a = 1.0f / Zd[45 + c];
      FT[(size_t)c * NB + bb] = f2bf((F_dist[(size_t)bb * 45 + c] - Zd[c]) * a);
    }
  } else {
    int idx = bid - NEXP * 3 - 32;
    int chunk = idx >> 5, tile = idx & 31;   // 5 chunks x 42 cols
    int bb = tile * 256 + threadIdx.x;
    for (int c = chunk * 42; c < chunk * 42 + 42; ++c) {
      float ac = 1.0f / Zc[NE + c];
      CT[(size_t)c * NB + bb] = f2bf((F_cos[(size_t)bb * NE + c] - Zc[c]) * ac);
      float as = 1.0f / Zs[NE + c];
      ST[(size_t)c * NB + bb] = f2bf((F_sin[(size_t)bb * NE + c] - Zs[c]) * as);
    }
  }
}

// ---------------- main: 3-layer MLP, 32x32x16 MFMA, h in registers --------
__global__ __launch_bounds__(512, 4) void k_main(
    const uint8_t* __restrict__ blob, const float* __restrict__ Dco,
    const uint16_t* __restrict__ FT, const uint16_t* __restrict__ CT,
    const uint16_t* __restrict__ ST,
    const int* __restrict__ IDX3, const int* __restrict__ IDX5,
    const float* __restrict__ b1, const float* __restrict__ b1s,
    float* __restrict__ out) {
  extern __shared__ __attribute__((aligned(16))) uint8_t smem[];
  // smem: [0:2K bias/wo][2048: Wh0 32K][34816: Wh1 32K]

  int bid = blockIdx.x;
  const int TOT = NEXP * NTILE;    // 6944, divisible by 8
  int lb = (bid & 7) * (TOT >> 3) + (bid >> 3);   // XCD-chunked swizzle
  int e = lb >> 5;
  int tile = lb & 31;
  int brow = tile * BT;

  int t = threadIdx.x;
  int w = t >> 6, lane = t & 63;
  int row = lane & 31, hi = lane >> 5;
  int hi4 = hi << 2;

  bool big = e < NE;
  int s = e - NE;
  const uint8_t* be = blob + (size_t)e * BLOB_STRIDE;

  // poly coeffs -> 9 named SGPR scalars (no array -> no scratch; R13)
  float d0 = __uint_as_float(__builtin_amdgcn_readfirstlane(__float_as_uint(Dco[0])));
  float d1 = __uint_as_float(__builtin_amdgcn_readfirstlane(__float_as_uint(Dco[1])));
  float d2 = __uint_as_float(__builtin_amdgcn_readfirstlane(__float_as_uint(Dco[2])));
  float d3 = __uint_as_float(__builtin_amdgcn_readfirstlane(__float_as_uint(Dco[3])));
  float d4 = __uint_as_float(__builtin_amdgcn_readfirstlane(__float_as_uint(Dco[4])));
  float d5 = __uint_as_float(__builtin_amdgcn_readfirstlane(__float_as_uint(Dco[5])));
  float d6 = __uint_as_float(__builtin_amdgcn_readfirstlane(__float_as_uint(Dco[6])));
  float d7 = __uint_as_float(__builtin_amdgcn_readfirstlane(__float_as_uint(Dco[7])));
  float d8 = __uint_as_float(__builtin_amdgcn_readfirstlane(__float_as_uint(Dco[8])));

  // ---- early VMEM (before glds: in-order vmcnt keeps staging in flight) --
  I4V bfr;
  bfr.i = make_int4(0, 0, 0, 0);
  if (hi == 0) {
    int bb = brow + w * 32 + row;
    if (big) {
      const int* ix = IDX3 + e * 6;          // block-uniform -> scalar loads
      unsigned g0 = FT[(size_t)ix[0] * NB + bb];
      unsigned g1 = FT[(size_t)ix[1] * NB + bb];
      unsigned g2 = FT[(size_t)ix[2] * NB + bb];
      unsigned g3 = FT[(size_t)ix[3] * NB + bb];
      unsigned g4 = FT[(size_t)ix[4] * NB + bb];
      unsigned g5 = FT[(size_t)ix[5] * NB + bb];
      unsigned cv = CT[(size_t)e * NB + bb];
      unsigned sv = ST[(size_t)e * NB + bb];
      bfr.u[0] = g0 | (g1 << 16);
      bfr.u[1] = g2 | (g3 << 16);
      bfr.u[2] = g4 | (g5 << 16);
      bfr.u[3] = cv | (sv << 16);
    } else {
      int id5 = IDX5[s];
      unsigned cv = CT[(size_t)id5 * NB + bb];
      unsigned sv = ST[(size_t)id5 * NB + bb];
      bfr.u[0] = cv | (sv << 16);
    }
  }
  const float* bias1 = big ? b1 + (size_t)e * H : b1s + (size_t)s * H;
  I4V aW[4];
  C16 c1[4];
#pragma unroll
  for (int mt = 0; mt < 4; ++mt) {
    aW[mt].i = *(const int4*)(be + (mt * 32 + row) * 32 + hi * 16);
#pragma unroll
    for (int i = 0; i < 4; ++i) {
      f32x4 q = *(const f32x4*)(bias1 + mt * 32 + i * 8 + hi4);
      c1[mt].q[i] = q * K2;     // acc1 = K2*(W1 F + b1)
    }
  }
  __builtin_amdgcn_sched_barrier(0);

  // ---- phase A staging: bias(2) + Wh0(32); phase B: Wh1(32) --------------
  for (int c = w; c < 34; c += 8)
    glds16(be + BIAS_OFF + c * 1024 + lane * 16, smem + c * 1024);
  __builtin_amdgcn_sched_barrier(0);
  for (int c = 34 + w; c < 66; c += 8)
    glds16(be + BIAS_OFF + c * 1024 + lane * 16, smem + c * 1024);
  __builtin_amdgcn_sched_barrier(0);

  // ---- layer 1 (K=16, real 8) + transition1, no LDS: overlaps staging ----
  f32x16 acc[4];
  bf16x8 bnA[8], bnB[8];
#pragma unroll
  for (int mt = 0; mt < 4; ++mt)
    acc[mt] = __builtin_amdgcn_mfma_f32_32x32x16_bf16(aW[mt].v, bfr.v, c1[mt].v, 0, 0, 0);
#pragma unroll
  for (int mt = 0; mt < 4; ++mt)
    trans_pair(acc[mt], bnA, 2 * mt, PD);

  // phase A done (each wave's 4 youngest VMEM = its phase-B glds)
  asm volatile("s_waitcnt vmcnt(4)" ::: "memory");
  __builtin_amdgcn_s_barrier();
  __builtin_amdgcn_sched_barrier(0);

  hidden_fused(acc, bnA, bnB, smem + 2048, (const float*)smem, row, hi, hi4, PD);

  asm volatile("s_waitcnt vmcnt(0)" ::: "memory");
  __builtin_amdgcn_s_barrier();
  __builtin_amdgcn_sched_barrier(0);

  float sum = hidden_out(acc, bnB, smem + 34816, (const float*)(smem + 512),
                         (const float*)(smem + 1024), row, hi, hi4, PD);

  // ---- output: atomic accumulate ----------------------------------------
  {
    float bout = *(const float*)(smem + 1536);
    sum += __shfl_xor(sum, 32);
    if (hi == 0)
      atomicAdd(out + brow + w * 32 + row, sum + bout);
  }
}

extern "C" void kernel_launch(void* const* d_in, const int* in_sizes, int n_in,
                              void* d_out, int out_size, void* d_ws, size_t ws_size,
                              hipStream_t stream) {
  const float* F_dist = (const float*)d_in[0];
  const float* F_cos  = (const float*)d_in[1];
  const float* F_sin  = (const float*)d_in[2];
  // d_in[3] F_angle unused by reference
  const float* Zd  = (const float*)d_in[4];
  const float* Zc  = (const float*)d_in[5];
  const float* Zs  = (const float*)d_in[6];
  const int* IDX3  = (const int*)d_in[7];
  const int* IDX5  = (const int*)d_in[8];
  const float* W1  = (const float*)d_in[9];
  const float* b1  = (const float*)d_in[10];
  const float* Wh  = (const float*)d_in[11];
  const float* bh  = (const float*)d_in[12];
  const float* Wo  = (const float*)d_in[13];
  const float* bo  = (const float*)d_in[14];
  const float* W1s = (const float*)d_in[15];
  const float* b1s = (const float*)d_in[16];
  const float* Whs = (const float*)d_in[17];
  const float* bhs = (const float*)d_in[18];
  const float* Wos = (const float*)d_in[19];
  const float* bos = (const float*)d_in[20];

  uint8_t* ws = (uint8_t*)d_ws;
  uint8_t* blob = ws;
  float* Dco   = (float*)(ws + O_COEF);
  uint16_t* FT = (uint16_t*)(ws + O_FT);
  uint16_t* CT = (uint16_t*)(ws + O_CT);
  uint16_t* ST = (uint16_t*)(ws + O_ST);

  hipFuncSetAttribute(reinterpret_cast<const void*>(k_main),
                      hipFuncAttributeMaxDynamicSharedMemorySize, SMEM_BYTES);

  k_fit<<<1, 64, 0, stream>>>(Dco);
  k_prep<<<NEXP * 3 + 32 + 160, 256, 0, stream>>>(
      W1, Wh, W1s, Whs, bh, bhs, Wo, Wos, bo, bos,
      F_dist, F_cos, F_sin, Zd, Zc, Zs, blob, FT, CT, ST, (float*)d_out);
  k_main<<<NEXP * NTILE, 512, SMEM_BYTES, stream>>>(
      blob, Dco, FT, CT, ST, IDX3, IDX5, b1, b1s, (float*)d_out);
}

// Round 21
// 220.244 us; speedup vs baseline: 1.1063x; 1.1063x over previous
//
#include <hip/hip_runtime.h>
#include <hip/hip_bf16.h>
#include <stdint.h>

#define NB 8192
#define NE 210
#define NS 7
#define NEXP 217
#define NI 8
#define H 128
#define BT 256
#define NTILE (NB / BT)          // 32
// blob per expert: [W1k 4K][bias 2K: bH0k,bH1k,wo,bo][Wh0k 32K][Wh1k 32K]
#define BLOB_STRIDE 71680
#define BIAS_OFF 4096
#define WH0_OFF 6144
#define WH1_OFF 38912
#define SMEM_BYTES 67584         // 2K bias + 64K Wh -> 2 blocks/CU
#define K2 2.8853900817779268f   // 2/ln2 : tanh(x) = 1 - 2/(1+2^(K2 x))

// ws layout (bytes); blob ends at 217*71680 = 15,554,560
#define O_FT 15560000u           // F_distT bf16 [45][8192]
#define O_CT 16300000u           // F_cosT  bf16 [210][8192]
#define O_ST 19750000u           // F_sinT  bf16 [210][8192]

typedef __attribute__((ext_vector_type(8))) short bf16x8;
typedef __attribute__((ext_vector_type(4))) float f32x4;
typedef __attribute__((ext_vector_type(16))) float f32x16;
typedef __attribute__((ext_vector_type(2))) int i32x2;

union I4V { int4 i; bf16x8 v; unsigned u[4]; };
union C16 { f32x16 v; f32x4 q[4]; };

__device__ __forceinline__ unsigned short f2bf(float f) {
  unsigned u = __float_as_uint(f);
  u += 0x7fffu + ((u >> 16) & 1u);
  return (unsigned short)(u >> 16);
}
// input already K2-scaled (weights/biases pre-multiplied by K2 at pack):
// tanh(x) = 1 - 2/(1+2^(K2 x)). exp2/rcp on the trans pipe -- measured
// cheaper than full-rate poly (R13), LDS table (R18), and hybrid (R20).
__device__ __forceinline__ float fast_tanh_s(float xs) {
  float e = __builtin_amdgcn_exp2f(xs);
  return 1.0f - 2.0f * __builtin_amdgcn_rcpf(1.0f + e);
}
__device__ __forceinline__ unsigned pk_bf16(float a, float b) {
  unsigned r;
  asm("v_cvt_pk_bf16_f32 %0, %1, %2" : "=v"(r) : "v"(a), "v"(b));
  return r;
}
__device__ __forceinline__ void glds16(const void* g, void* l) {
  __builtin_amdgcn_global_load_lds(
      (const __attribute__((address_space(1))) unsigned int*)g,
      (__attribute__((address_space(3))) unsigned int*)l, 16, 0, 0);
}

// ---- transition slice pair for one acc tile (verified R5 permlane map) ----
__device__ __forceinline__ void trans_pair(const f32x16& a, bf16x8 (&bn)[8], int base) {
#pragma unroll
  for (int half = 0; half < 2; ++half) {
    const int ko = half * 8;
    unsigned P0 = pk_bf16(fast_tanh_s(a[ko + 0]), fast_tanh_s(a[ko + 1]));
    unsigned P1 = pk_bf16(fast_tanh_s(a[ko + 2]), fast_tanh_s(a[ko + 3]));
    unsigned P2 = pk_bf16(fast_tanh_s(a[ko + 4]), fast_tanh_s(a[ko + 5]));
    unsigned P3 = pk_bf16(fast_tanh_s(a[ko + 6]), fast_tanh_s(a[ko + 7]));
    i32x2 s0 = __builtin_amdgcn_permlane32_swap((int)P0, (int)P2, false, false);
    i32x2 s1 = __builtin_amdgcn_permlane32_swap((int)P1, (int)P3, false, false);
    I4V r;
    r.u[0] = (unsigned)s0.x;   // w0
    r.u[1] = (unsigned)s1.x;   // w1
    r.u[2] = (unsigned)s0.y;   // w2
    r.u[3] = (unsigned)s1.y;   // w3
    bn[base + half] = r.v;
  }
}

// ---- hidden layer fused with next-layer transition: mt-outer so that
// acc[mt]'s trans slices fill the MFMA dependency gaps of acc[mt+1] ---------
__device__ __forceinline__ void hidden_fused(f32x16 (&acc)[4], const bf16x8 (&bnIn)[8],
                                             bf16x8 (&bnOut)[8],
                                             const uint8_t* wb, const float* biaL,
                                             int row, int hi, int hi4) {
  __builtin_amdgcn_s_setprio(1);
#pragma unroll
  for (int mt = 0; mt < 4; ++mt) {
    int soff0 = (hi ^ (row & 15)) << 4;
    bf16x8 aF = *(const bf16x8*)(wb + (mt * 32 + row) * 256 + soff0);
    C16 c0;
#pragma unroll
    for (int i = 0; i < 4; ++i)
      c0.q[i] = *(const f32x4*)(biaL + mt * 32 + i * 8 + hi4);
    acc[mt] = __builtin_amdgcn_mfma_f32_32x32x16_bf16(aF, bnIn[0], c0.v, 0, 0, 0);
#pragma unroll
    for (int kk = 1; kk < 8; ++kk) {
      int soff = ((2 * kk + hi) ^ (row & 15)) << 4;
      bf16x8 aF2 = *(const bf16x8*)(wb + (mt * 32 + row) * 256 + soff);
      acc[mt] = __builtin_amdgcn_mfma_f32_32x32x16_bf16(aF2, bnIn[kk], acc[mt], 0, 0, 0);
    }
    trans_pair(acc[mt], bnOut, 2 * mt);
  }
  __builtin_amdgcn_s_setprio(0);
}

// ---- last hidden layer fused with output tanh-dot -------------------------
__device__ __forceinline__ float hidden_out(f32x16 (&acc)[4], const bf16x8 (&bnIn)[8],
                                            const uint8_t* wb, const float* biaL,
                                            const float* woL,
                                            int row, int hi, int hi4) {
  float sum = 0.f;
  __builtin_amdgcn_s_setprio(1);
#pragma unroll
  for (int mt = 0; mt < 4; ++mt) {
    int soff0 = (hi ^ (row & 15)) << 4;
    bf16x8 aF = *(const bf16x8*)(wb + (mt * 32 + row) * 256 + soff0);
    C16 c0;
#pragma unroll
    for (int i = 0; i < 4; ++i)
      c0.q[i] = *(const f32x4*)(biaL + mt * 32 + i * 8 + hi4);
    acc[mt] = __builtin_amdgcn_mfma_f32_32x32x16_bf16(aF, bnIn[0], c0.v, 0, 0, 0);
#pragma unroll
    for (int kk = 1; kk < 8; ++kk) {
      int soff = ((2 * kk + hi) ^ (row & 15)) << 4;
      bf16x8 aF2 = *(const bf16x8*)(wb + (mt * 32 + row) * 256 + soff);
      acc[mt] = __builtin_amdgcn_mfma_f32_32x32x16_bf16(aF2, bnIn[kk], acc[mt], 0, 0, 0);
    }
#pragma unroll
    for (int i = 0; i < 4; ++i) {
      f32x4 wq = *(const f32x4*)(woL + mt * 32 + i * 8 + hi4);
#pragma unroll
      for (int j = 0; j < 4; ++j)
        sum += fast_tanh_s(acc[mt][4 * i + j]) * wq[j];
    }
  }
  __builtin_amdgcn_s_setprio(0);
  return sum;
}

// ---------------- prep: weight pack (K2-prescale) + transpose + out-zero --
__global__ __launch_bounds__(256) void k_prep(
    const float* __restrict__ W1, const float* __restrict__ Wh,
    const float* __restrict__ W1s, const float* __restrict__ Whs,
    const float* __restrict__ bh, const float* __restrict__ bhs,
    const float* __restrict__ Wo, const float* __restrict__ Wos,
    const float* __restrict__ bo, const float* __restrict__ bos,
    const float* __restrict__ F_dist, const float* __restrict__ F_cos,
    const float* __restrict__ F_sin,
    const float* __restrict__ Zd, const float* __restrict__ Zc,
    const float* __restrict__ Zs,
    uint8_t* __restrict__ blob, uint16_t* __restrict__ FT,
    uint16_t* __restrict__ CT, uint16_t* __restrict__ ST,
    float* __restrict__ outZ) {
  int bid = blockIdx.x;
  if (bid < NEXP * 3) {
    int n = threadIdx.x;
    if (n >= 128) return;
    int e = bid / 3, sec = bid % 3;
    uint8_t* be = blob + (size_t)e * BLOB_STRIDE;
    bool big = e < NE;
    int s = e - NE;
    if (sec == 0) {
      union { int4 v[2]; unsigned short u[16]; } row;
      row.v[0] = make_int4(0, 0, 0, 0);
      row.v[1] = make_int4(0, 0, 0, 0);
      if (big) {
        for (int k = 0; k < NI; ++k) row.u[k] = f2bf(K2 * W1[((size_t)e * NI + k) * H + n]);
      } else {
        for (int k = 0; k < 2; ++k) row.u[k] = f2bf(K2 * W1s[((size_t)s * 2 + k) * H + n]);
      }
      *(int4*)(be + n * 32) = row.v[0];
      *(int4*)(be + n * 32 + 16) = row.v[1];
      float* bsec = (float*)(be + BIAS_OFF);
      bsec[n]       = K2 * (big ? bh[(size_t)e * H + n]        : bhs[(size_t)s * H + n]);
      bsec[128 + n] = K2 * (big ? bh[((size_t)NE + e) * H + n] : bhs[((size_t)NS + s) * H + n]);
      bsec[256 + n] = big ? Wo[(size_t)e * H + n] : Wos[(size_t)s * H + n];
      if (n == 0) bsec[384] = big ? bo[e] : bos[s];
    } else {
      int l = sec - 1;
      union { int4 v[16]; unsigned short u[128]; } row;
      if (big) {
        for (int k = 0; k < H; ++k)
          row.u[k] = f2bf(K2 * Wh[(((size_t)l * NE + e) * H + k) * H + n]);
      } else {
        for (int k = 0; k < H; ++k)
          row.u[k] = f2bf(K2 * Whs[(((size_t)l * NS + s) * H + k) * H + n]);
      }
      int4* dst = (int4*)(be + (l ? WH1_OFF : WH0_OFF) + n * 256);
      for (int c = 0; c < 16; ++c) dst[c] = row.v[c ^ (n & 15)];
    }
  } else if (bid < NEXP * 3 + 32) {
    int tile = bid - NEXP * 3;
    int bb = tile * 256 + threadIdx.x;
    outZ[bb] = 0.f;                     // folded d_out zeroing (32x256 = 8192)
    for (int c = 0; c < 45; ++c) {
      float a = 1.0f / Zd[45 + c];
      FT[(size_t)c * NB + bb] = f2bf((F_dist[(size_t)bb * 45 + c] - Zd[c]) * a);
    }
  } else {
    int idx = bid - NEXP * 3 - 32;
    int chunk = idx >> 5, tile = idx & 31;   // 5 chunks x 42 cols
    int bb = tile * 256 + threadIdx.x;
    for (int c = chunk * 42; c < chunk * 42 + 42; ++c) {
      float ac = 1.0f / Zc[NE + c];
      CT[(size_t)c * NB + bb] = f2bf((F_cos[(size_t)bb * NE + c] - Zc[c]) * ac);
      float as = 1.0f / Zs[NE + c];
      ST[(size_t)c * NB + bb] = f2bf((F_sin[(size_t)bb * NE + c] - Zs[c]) * as);
    }
  }
}

// ---------------- main: 3-layer MLP, 32x32x16 MFMA, h in registers --------
// mt-outer fused layers: trans slices of acc[mt] overlap acc[mt+1]'s MFMA
// chain within the wave. Inputs from pre-transposed bf16; atomic output.
__global__ __launch_bounds__(512, 4) void k_main(
    const uint8_t* __restrict__ blob,
    const uint16_t* __restrict__ FT, const uint16_t* __restrict__ CT,
    const uint16_t* __restrict__ ST,
    const int* __restrict__ IDX3, const int* __restrict__ IDX5,
    const float* __restrict__ b1, const float* __restrict__ b1s,
    float* __restrict__ out) {
  extern __shared__ __attribute__((aligned(16))) uint8_t smem[];
  // smem: [0:2K bias/wo][2048: Wh0 32K][34816: Wh1 32K]

  int bid = blockIdx.x;
  const int TOT = NEXP * NTILE;    // 6944, divisible by 8
  int lb = (bid & 7) * (TOT >> 3) + (bid >> 3);   // XCD-chunked swizzle
  int e = lb >> 5;
  int tile = lb & 31;
  int brow = tile * BT;

  int t = threadIdx.x;
  int w = t >> 6, lane = t & 63;
  int row = lane & 31, hi = lane >> 5;
  int hi4 = hi << 2;

  bool big = e < NE;
  int s = e - NE;
  const uint8_t* be = blob + (size_t)e * BLOB_STRIDE;

  // ---- early VMEM (issued BEFORE glds: in-order vmcnt => waiting on these
  //      does not drain the staging queue) ---------------------------------
  I4V bfr;
  bfr.i = make_int4(0, 0, 0, 0);
  if (hi == 0) {
    int bb = brow + w * 32 + row;
    if (big) {
      const int* ix = IDX3 + e * 6;          // block-uniform -> scalar loads
      unsigned g0 = FT[(size_t)ix[0] * NB + bb];
      unsigned g1 = FT[(size_t)ix[1] * NB + bb];
      unsigned g2 = FT[(size_t)ix[2] * NB + bb];
      unsigned g3 = FT[(size_t)ix[3] * NB + bb];
      unsigned g4 = FT[(size_t)ix[4] * NB + bb];
      unsigned g5 = FT[(size_t)ix[5] * NB + bb];
      unsigned cv = CT[(size_t)e * NB + bb];
      unsigned sv = ST[(size_t)e * NB + bb];
      bfr.u[0] = g0 | (g1 << 16);
      bfr.u[1] = g2 | (g3 << 16);
      bfr.u[2] = g4 | (g5 << 16);
      bfr.u[3] = cv | (sv << 16);
    } else {
      int id5 = IDX5[s];
      unsigned cv = CT[(size_t)id5 * NB + bb];
      unsigned sv = ST[(size_t)id5 * NB + bb];
      bfr.u[0] = cv | (sv << 16);
    }
  }
  const float* bias1 = big ? b1 + (size_t)e * H : b1s + (size_t)s * H;
  I4V aW[4];
  C16 c1[4];
#pragma unroll
  for (int mt = 0; mt < 4; ++mt) {
    aW[mt].i = *(const int4*)(be + (mt * 32 + row) * 32 + hi * 16);
#pragma unroll
    for (int i = 0; i < 4; ++i) {
      f32x4 q = *(const f32x4*)(bias1 + mt * 32 + i * 8 + hi4);
      c1[mt].q[i] = q * K2;     // acc1 = K2*(W1 F + b1)
    }
  }
  __builtin_amdgcn_sched_barrier(0);

  // ---- phase A staging: bias(2) + Wh0(32) chunks; phase B: Wh1(32) -------
  for (int c = w; c < 34; c += 8)
    glds16(be + BIAS_OFF + c * 1024 + lane * 16, smem + c * 1024);
  __builtin_amdgcn_sched_barrier(0);
  for (int c = 34 + w; c < 66; c += 8)
    glds16(be + BIAS_OFF + c * 1024 + lane * 16, smem + c * 1024);
  __builtin_amdgcn_sched_barrier(0);

  // ---- layer 1 (K=16, real 8) + transition1, no LDS: overlaps staging ----
  f32x16 acc[4];
  bf16x8 bnA[8], bnB[8];
#pragma unroll
  for (int mt = 0; mt < 4; ++mt)
    acc[mt] = __builtin_amdgcn_mfma_f32_32x32x16_bf16(aW[mt].v, bfr.v, c1[mt].v, 0, 0, 0);
#pragma unroll
  for (int mt = 0; mt < 4; ++mt)
    trans_pair(acc[mt], bnA, 2 * mt);

  // phase A done (each wave's 4 youngest VMEM = its phase-B glds)
  asm volatile("s_waitcnt vmcnt(4)" ::: "memory");
  __builtin_amdgcn_s_barrier();
  __builtin_amdgcn_sched_barrier(0);

  hidden_fused(acc, bnA, bnB, smem + 2048, (const float*)smem, row, hi, hi4);

  asm volatile("s_waitcnt vmcnt(0)" ::: "memory");
  __builtin_amdgcn_s_barrier();
  __builtin_amdgcn_sched_barrier(0);

  float sum = hidden_out(acc, bnB, smem + 34816, (const float*)(smem + 512),
                         (const float*)(smem + 1024), row, hi, hi4);

  // ---- output: atomic accumulate ----------------------------------------
  {
    float bout = *(const float*)(smem + 1536);
    sum += __shfl_xor(sum, 32);
    if (hi == 0)
      atomicAdd(out + brow + w * 32 + row, sum + bout);
  }
}

extern "C" void kernel_launch(void* const* d_in, const int* in_sizes, int n_in,
                              void* d_out, int out_size, void* d_ws, size_t ws_size,
                              hipStream_t stream) {
  const float* F_dist = (const float*)d_in[0];
  const float* F_cos  = (const float*)d_in[1];
  const float* F_sin  = (const float*)d_in[2];
  // d_in[3] F_angle unused by reference
  const float* Zd  = (const float*)d_in[4];
  const float* Zc  = (const float*)d_in[5];
  const float* Zs  = (const float*)d_in[6];
  const int* IDX3  = (const int*)d_in[7];
  const int* IDX5  = (const int*)d_in[8];
  const float* W1  = (const float*)d_in[9];
  const float* b1  = (const float*)d_in[10];
  const float* Wh  = (const float*)d_in[11];
  const float* bh  = (const float*)d_in[12];
  const float* Wo  = (const float*)d_in[13];
  const float* bo  = (const float*)d_in[14];
  const float* W1s = (const float*)d_in[15];
  const float* b1s = (const float*)d_in[16];
  const float* Whs = (const float*)d_in[17];
  const float* bhs = (const float*)d_in[18];
  const float* Wos = (const float*)d_in[19];
  const float* bos = (const float*)d_in[20];

  uint8_t* ws = (uint8_t*)d_ws;
  uint8_t* blob = ws;
  uint16_t* FT = (uint16_t*)(ws + O_FT);
  uint16_t* CT = (uint16_t*)(ws + O_CT);
  uint16_t* ST = (uint16_t*)(ws + O_ST);

  hipFuncSetAttribute(reinterpret_cast<const void*>(k_main),
                      hipFuncAttributeMaxDynamicSharedMemorySize, SMEM_BYTES);

  k_prep<<<NEXP * 3 + 32 + 160, 256, 0, stream>>>(
      W1, Wh, W1s, Whs, bh, bhs, Wo, Wos, bo, bos,
      F_dist, F_cos, F_sin, Zd, Zc, Zs, blob, FT, CT, ST, (float*)d_out);
  k_main<<<NEXP * NTILE, 512, SMEM_BYTES, stream>>>(
      blob, FT, CT, ST, IDX3, IDX5, b1, b1s, (float*)d_out);
}